// Round 9
// baseline (273.508 us; speedup 1.0000x reference)
//
#include <hip/hip_runtime.h>
#include <math.h>

#define SEQLEN 2048
#define DIN 2048
#define NH 32
#define NKV 8
#define HD 64
#define DQ (NH*HD)    // 2048
#define DKV (NKV*HD)  // 512

using u16 = unsigned short;
using u32 = unsigned int;
using bf16x8 = __attribute__((ext_vector_type(8))) __bf16;
using f32x4  = __attribute__((ext_vector_type(4))) float;

__device__ __forceinline__ u16 f2b(float f) {
    union { float f; u32 u; } x; x.f = f;
    u32 u = x.u;
    u32 r = (u + 0x7fffu + ((u >> 16) & 1u)) >> 16;   // RNE
    return (u16)r;
}
__device__ __forceinline__ float b2f(u16 h) {
    union { u32 u; float f; } x; x.u = (u32)h << 16; return x.f;
}
__device__ __forceinline__ u32 fbits(float f) {
    union { float f; u32 u; } x; x.f = f; return x.u;
}

// async global->LDS, 16B/lane; lds base wave-uniform, lane i writes i*16B.
__device__ __forceinline__ void gl2lds16(const u16* g, u16* l) {
    __builtin_amdgcn_global_load_lds(
        (const __attribute__((address_space(1))) void*)g,
        (__attribute__((address_space(3))) void*)l,
        16, 0, 0);
}

// --- 8-row x 64-k chunks (512 u16) for attention tiles ----------------------
__device__ __forceinline__ int lds_off(int row, int kk0) {
    return (row >> 3) * 512 + (kk0 >> 3) * 64 + (row & 7) * 8;
}
// --- 16-row x 32-k chunks (512 u16) for GEMM tiles --------------------------
__device__ __forceinline__ int lds_off32(int row, int kk0) {
    return (row >> 4) * 512 + (kk0 >> 3) * 128 + (row & 15) * 8;
}

// ---------------------------------------------------------------------------
// Fused prep: cast x -> bf16; transpose-cast wq/wk/wv (contiguous [3072][2048])
// and wo.
// ---------------------------------------------------------------------------
__global__ __launch_bounds__(256) void prep(const float* __restrict__ x,
                                            const float* __restrict__ wq,
                                            const float* __restrict__ wk,
                                            const float* __restrict__ wv,
                                            const float* __restrict__ wo,
                                            u16* __restrict__ xb,
                                            u16* __restrict__ wqkvT,
                                            u16* __restrict__ woT) {
    const int b = blockIdx.x;
    const int t = threadIdx.x;
    if (b < 4096) {
        int i = b * 1024 + t * 4;
        float4 v = *reinterpret_cast<const float4*>(&x[i]);
        ushort4 o;
        o.x = f2b(v.x); o.y = f2b(v.y); o.z = f2b(v.z); o.w = f2b(v.w);
        *reinterpret_cast<ushort4*>(&xb[i]) = o;
        return;
    }
    __shared__ float tile[32][33];
    int b2 = b - 4096;
    const float* src; u16* dst; int C, bx, by;
    if (b2 < 4096)      { src = wq; dst = wqkvT;                           C = 2048; bx = b2 & 63; by = b2 >> 6; }
    else if (b2 < 5120) { b2 -= 4096; src = wk; dst = wqkvT + (size_t)2048 * 2048; C = 512; bx = b2 & 15; by = b2 >> 4; }
    else if (b2 < 6144) { b2 -= 5120; src = wv; dst = wqkvT + (size_t)2560 * 2048; C = 512; bx = b2 & 15; by = b2 >> 4; }
    else                { b2 -= 6144; src = wo; dst = woT;                 C = 2048; bx = b2 & 63; by = b2 >> 6; }
    const int c0 = bx * 32, r0 = by * 32;
    const int tr = t >> 5, tc = t & 31;
    #pragma unroll
    for (int i = 0; i < 4; ++i)
        tile[tr + i * 8][tc] = src[(size_t)(r0 + tr + i * 8) * C + c0 + tc];
    __syncthreads();
    #pragma unroll
    for (int i = 0; i < 4; ++i)
        dst[(size_t)(c0 + tr + i * 8) * 2048 + r0 + tc] = f2b(tile[tc][tr + i * 8]);
}

// ---------------------------------------------------------------------------
// QKV GEMM v10: r4/r8's SPLIT-K thick loop (best verified 60.6us, 425 TF at
// 3 blocks/CU; r8 proved counted-vmcnt neutral here) with BF16 PARTIALS:
// halves the split-K HBM tax (WRITE 49.4 -> 24.7 MB, reduce reads halve).
// Precision: partials ~N(0,0.5), bf16 RNE err ~2^-9 rel -- below the bf16
// input rounding already present (absmax headroom 4x). Thick step: BM=BN=128,
// 16 MFMA + 8 b128 ds_read per wave-step. Grid (24,16,2)=768 = 3/CU.
// ---------------------------------------------------------------------------
__global__ __launch_bounds__(256) void gemm_splitk(const u16* __restrict__ A,
                                                   const u16* __restrict__ Bt,
                                                   u16* __restrict__ P) {
    __shared__ u16 As[3][128 * 32];   // 3 bufs x 8KB
    __shared__ u16 Bs[3][128 * 32];   // 3 bufs x 8KB  (48KB total)
    const int t = threadIdx.x;
    const int w = t >> 6, lane = t & 63, quad = lane >> 4, l15 = lane & 15;
    const int m0 = blockIdx.y * 128, n0 = blockIdx.x * 128;
    const int kb = blockIdx.z << 10;                 // 0 or 1024
    u16* Cp = P + (size_t)blockIdx.z * (2048 * 3072);
    const int wr = (w >> 1) * 64, wc = (w & 1) * 64;
    const int srow = lane & 15, skoct = (lane >> 4) * 8;
    const int K = 2048, N = 3072;

    f32x4 acc[4][4];
    #pragma unroll
    for (int mt = 0; mt < 4; ++mt)
        #pragma unroll
        for (int nt = 0; nt < 4; ++nt)
            #pragma unroll
            for (int r = 0; r < 4; ++r) acc[mt][nt][r] = 0.0f;

    auto stage = [&](int buf, int st) {
        const int k0 = st << 5;
        #pragma unroll
        for (int i = 0; i < 2; ++i) {
            int c = w * 2 + i;
            gl2lds16(A  + (size_t)(m0 + c * 16 + srow) * K + kb + k0 + skoct, &As[buf][c * 512]);
            gl2lds16(Bt + (size_t)(n0 + c * 16 + srow) * K + kb + k0 + skoct, &Bs[buf][c * 512]);
        }
    };

    const int nsteps = 32;                           // K/2 / 32
    stage(0, 0);
    stage(1, 1);
    int cur = 0;
    for (int st = 0; st < nsteps; ++st) {
        if (st < nsteps - 1) asm volatile("s_waitcnt vmcnt(4)" ::: "memory");
        else                 asm volatile("s_waitcnt vmcnt(0)" ::: "memory");
        __builtin_amdgcn_s_barrier();
        asm volatile("" ::: "memory");               // no ds_read hoist
        if (st + 2 < nsteps) {
            int tgt = (cur == 0) ? 2 : cur - 1;      // buf (st+2)%3, read at st-1
            stage(tgt, st + 2);
        }
        const int kk0 = quad * 8;
        bf16x8 a[4], b[4];
        #pragma unroll
        for (int mt = 0; mt < 4; ++mt)
            a[mt] = *reinterpret_cast<const bf16x8*>(&As[cur][lds_off32(wr + mt * 16 + l15, kk0)]);
        #pragma unroll
        for (int nt = 0; nt < 4; ++nt)
            b[nt] = *reinterpret_cast<const bf16x8*>(&Bs[cur][lds_off32(wc + nt * 16 + l15, kk0)]);
        #pragma unroll
        for (int mt = 0; mt < 4; ++mt)
            #pragma unroll
            for (int nt = 0; nt < 4; ++nt)
                acc[mt][nt] = __builtin_amdgcn_mfma_f32_16x16x32_bf16(a[mt], b[nt], acc[mt][nt], 0, 0, 0);
        cur = (cur == 2) ? 0 : cur + 1;
    }

    #pragma unroll
    for (int mt = 0; mt < 4; ++mt)
        #pragma unroll
        for (int nt = 0; nt < 4; ++nt) {
            const int rb  = m0 + wr + mt * 16 + quad * 4;
            const int col = n0 + wc + nt * 16 + l15;
            #pragma unroll
            for (int r = 0; r < 4; ++r)
                Cp[(size_t)(rb + r) * N + col] = f2b(acc[mt][nt][r]);
        }
}

// ---------------------------------------------------------------------------
// qkv_reduce v2 (bf16 partials in): P0+P1 -> fused RMSNorm+RoPE (Q/K) or
// interleave-transpose (V). Grid (32 s-tiles, 48 heads), 256 thr. Thread t:
// row r=t>>2, d-chunk q=t&3. 4-lane groups share a row: shfl_xor 1,2 for the
// RMS sum; RoPE partner d^32 at lane t^2. Q pre-scaled by 0.125*log2(e).
// V heads: interleave cl(r) = bit-perm of r, via an 8KB LDS transpose.
// ---------------------------------------------------------------------------
__global__ __launch_bounds__(256) void qkv_reduce(const u16* __restrict__ P,
                                                  u16* __restrict__ Qb,
                                                  u16* __restrict__ Kb,
                                                  u16* __restrict__ VtG,
                                                  const float* __restrict__ cosb,
                                                  const float* __restrict__ sinb,
                                                  const float* __restrict__ qnw,
                                                  const float* __restrict__ knw) {
    __shared__ u16 Vl[64][64];
    const int s0 = blockIdx.x * 64;
    const int h  = blockIdx.y;                    // 0..31 Q, 32..39 K, 40..47 V
    const int t  = threadIdx.x;
    const int r  = t >> 2, q = t & 3;
    const int s  = s0 + r;

    const u16* p0 = P + (size_t)s * 3072 + h * 64 + q * 16;
    const u16* p1 = p0 + (size_t)2048 * 3072;
    float v[16];
    #pragma unroll
    for (int c = 0; c < 2; ++c) {
        uint4 a = *reinterpret_cast<const uint4*>(p0 + c * 8);
        uint4 b = *reinterpret_cast<const uint4*>(p1 + c * 8);
        const u32* aw = reinterpret_cast<const u32*>(&a);
        const u32* bw = reinterpret_cast<const u32*>(&b);
        #pragma unroll
        for (int j = 0; j < 4; ++j) {
            v[c*8 + j*2]     = b2f((u16)(aw[j] & 0xffffu)) + b2f((u16)(bw[j] & 0xffffu));
            v[c*8 + j*2 + 1] = b2f((u16)(aw[j] >> 16))     + b2f((u16)(bw[j] >> 16));
        }
    }

    if (h >= 40) {                                // ---- V ----
        const int a4 = (r >> 4) & 3, b4 = (r >> 2) & 3;
        const int cl = (b4 * 2 + (a4 >> 1)) * 8 + (a4 & 1) * 4 + (r & 3);
        #pragma unroll
        for (int i = 0; i < 16; ++i) Vl[q * 16 + i][cl] = f2b(v[i]);
        __syncthreads();
        u16* dst = VtG + (size_t)((h - 40) * 64 + r) * 2048 + s0 + q * 16;
        #pragma unroll
        for (int i = 0; i < 4; ++i)
            *reinterpret_cast<ushort4*>(dst + i * 4) =
                *reinterpret_cast<const ushort4*>(&Vl[r][q * 16 + i * 4]);
        return;
    }

    const bool isQ = h < 32;
    const float* nw = isQ ? qnw : knw;
    float s2 = 0.0f;
    #pragma unroll
    for (int i = 0; i < 16; ++i) s2 += v[i] * v[i];
    s2 += __shfl_xor(s2, 1);
    s2 += __shfl_xor(s2, 2);
    const float rin = rsqrtf(s2 * (1.0f / 64.0f) + 1e-6f);

    float vn[16];
    #pragma unroll
    for (int i = 0; i < 16; ++i) vn[i] = v[i] * rin * nw[q * 16 + i];

    const float sgn = (q < 2) ? -1.0f : 1.0f;     // rotate_half sign
    float res[16];
    #pragma unroll
    for (int i = 0; i < 16; ++i) {
        const int d = q * 16 + i;
        float c  = cosb[s * 64 + d];
        float sn = sinb[s * 64 + d];
        float vp = __shfl_xor(vn[i], 2);          // partner d^32
        res[i] = vn[i] * c + sgn * vp * sn;
    }

    u16* dst;
    if (isQ) {
        #pragma unroll
        for (int i = 0; i < 16; ++i) res[i] *= 0.18033688f;   // 0.125*log2(e)
        dst = Qb + (size_t)s * 2048 + h * 64 + q * 16;
    } else {
        dst = Kb + (size_t)s * 512 + (h - 32) * 64 + q * 16;
    }
    #pragma unroll
    for (int i = 0; i < 4; ++i) {
        ushort4 o;
        o.x = f2b(res[i*4+0]); o.y = f2b(res[i*4+1]);
        o.z = f2b(res[i*4+2]); o.w = f2b(res[i*4+3]);
        *reinterpret_cast<ushort4*>(dst + i * 4) = o;
    }
}

// ---------------------------------------------------------------------------
// Out-projection GEMM v3: SPLIT-K=2, thin step (BM=64, BN=128), counted
// depth-2, grid (16,32,2) = 1024 blocks = 4/CU (was 512 = 2/CU). bf16
// partials -> out_reduce. Doubling TLP on the thin step is the only lever
// that moved it (r1->r2 +8%); split-K halves per-block steps to 32.
// ---------------------------------------------------------------------------
__global__ __launch_bounds__(256) void gemm_outk(const u16* __restrict__ A,
                                                 const u16* __restrict__ Bt,
                                                 u16* __restrict__ Po) {
    __shared__ u16 As[3][64 * 32];    // 3 x 4KB
    __shared__ u16 Bs[3][128 * 32];   // 3 x 8KB  (36KB total)
    const int t = threadIdx.x;
    const int w = t >> 6, lane = t & 63, quad = lane >> 4, l15 = lane & 15;
    const int m0 = blockIdx.y * 64, n0 = blockIdx.x * 128;
    const int kb = blockIdx.z << 10;                 // 0 or 1024
    u16* Cp = Po + (size_t)blockIdx.z * (2048 * 2048);
    const int wr = (w >> 1) * 32, wc = (w & 1) * 64;
    const int srow = lane & 15, skoct = (lane >> 4) * 8;
    const int K = 2048, N = 2048;

    f32x4 acc[2][4];
    #pragma unroll
    for (int mt = 0; mt < 2; ++mt)
        #pragma unroll
        for (int nt = 0; nt < 4; ++nt)
            #pragma unroll
            for (int r = 0; r < 4; ++r) acc[mt][nt][r] = 0.0f;

    auto stage = [&](int buf, int st) {
        const int k0 = st << 5;
        gl2lds16(A + (size_t)(m0 + w * 16 + srow) * K + kb + k0 + skoct, &As[buf][w * 512]);
        #pragma unroll
        for (int i = 0; i < 2; ++i) {
            int c = w * 2 + i;
            gl2lds16(Bt + (size_t)(n0 + c * 16 + srow) * K + kb + k0 + skoct, &Bs[buf][c * 512]);
        }
    };

    const int nsteps = 32;                           // (K/2) / 32
    stage(0, 0);
    stage(1, 1);
    int cur = 0;
    for (int st = 0; st < nsteps; ++st) {
        if (st < nsteps - 1) asm volatile("s_waitcnt vmcnt(3)" ::: "memory");
        else                 asm volatile("s_waitcnt vmcnt(0)" ::: "memory");
        __builtin_amdgcn_s_barrier();
        asm volatile("" ::: "memory");
        if (st + 2 < nsteps) {
            int tgt = (cur == 0) ? 2 : cur - 1;
            stage(tgt, st + 2);
        }
        const int kk0 = quad * 8;
        bf16x8 a[2], b[4];
        #pragma unroll
        for (int mt = 0; mt < 2; ++mt)
            a[mt] = *reinterpret_cast<const bf16x8*>(&As[cur][lds_off32(wr + mt * 16 + l15, kk0)]);
        #pragma unroll
        for (int nt = 0; nt < 4; ++nt)
            b[nt] = *reinterpret_cast<const bf16x8*>(&Bs[cur][lds_off32(wc + nt * 16 + l15, kk0)]);
        #pragma unroll
        for (int mt = 0; mt < 2; ++mt)
            #pragma unroll
            for (int nt = 0; nt < 4; ++nt)
                acc[mt][nt] = __builtin_amdgcn_mfma_f32_16x16x32_bf16(a[mt], b[nt], acc[mt][nt], 0, 0, 0);
        cur = (cur == 2) ? 0 : cur + 1;
    }

    #pragma unroll
    for (int mt = 0; mt < 2; ++mt)
        #pragma unroll
        for (int nt = 0; nt < 4; ++nt) {
            const int rb  = m0 + wr + mt * 16 + quad * 4;
            const int col = n0 + wc + nt * 16 + l15;
            #pragma unroll
            for (int r = 0; r < 4; ++r)
                Cp[(size_t)(rb + r) * N + col] = f2b(acc[mt][nt][r]);
        }
}

// ---------------------------------------------------------------------------
// out_reduce: out = fp32(P0 + P1). 4.19M elems, 8/thread, grid 2048.
// ---------------------------------------------------------------------------
__global__ __launch_bounds__(256) void out_reduce(const u16* __restrict__ Po,
                                                  float* __restrict__ out) {
    const size_t i = ((size_t)blockIdx.x * 256 + threadIdx.x) * 8;
    uint4 a = *reinterpret_cast<const uint4*>(Po + i);
    uint4 b = *reinterpret_cast<const uint4*>(Po + (size_t)2048 * 2048 + i);
    const u32* aw = reinterpret_cast<const u32*>(&a);
    const u32* bw = reinterpret_cast<const u32*>(&b);
    float r[8];
    #pragma unroll
    for (int j = 0; j < 4; ++j) {
        r[j*2]   = b2f((u16)(aw[j] & 0xffffu)) + b2f((u16)(bw[j] & 0xffffu));
        r[j*2+1] = b2f((u16)(aw[j] >> 16))     + b2f((u16)(bw[j] >> 16));
    }
    float4 o0 = {r[0], r[1], r[2], r[3]};
    float4 o1 = {r[4], r[5], r[6], r[7]};
    *reinterpret_cast<float4*>(&out[i])     = o0;
    *reinterpret_cast<float4*>(&out[i + 4]) = o1;
}

// ---------------------------------------------------------------------------
// MFMA flash attention v6: r8 structure + T5 s_setprio(1) around the MFMA
// clusters (m191: +4-7% on attn; GEMM-neutral m190 so applied here only).
// counted-vmcnt depth-2 (3 K/V bufs) + kvh = b&7 (== XCD) L2-resident K/V.
// qt = 31-(b>>5) heavy-first. Block = ONE head x 64 q-rows. Fixed-shift
// softmax p=exp2(s-24). PV uses FULL K=32 MFMAs via column-interleaved V.
// ---------------------------------------------------------------------------
__global__ __launch_bounds__(256) void attn_fused(const u16* __restrict__ Qb,
                                                  const u16* __restrict__ Kb,
                                                  const u16* __restrict__ VtG,
                                                  u16* __restrict__ attnb) {
    __shared__ u16 Ks[3][4096];
    __shared__ u16 Vt[3][4096];

    const int b    = blockIdx.x;
    const int kvh  = b & 7;
    const int qt   = 31 - (b >> 5);
    const int q0   = qt * 64;
    const int h    = kvh * 4 + ((b >> 3) & 3);
    const int t    = threadIdx.x;
    const int w    = t >> 6, lane = t & 63, quad = lane >> 4, l15 = lane & 15;
    const int srow = lane & 7, soct = (lane >> 3) * 8;
    const int qrow = q0 + w * 16 + l15;

    const u16* qr = Qb + (size_t)qrow * DQ + h * HD;
    bf16x8 qB[2];
    qB[0] = *reinterpret_cast<const bf16x8*>(qr + quad * 8);
    qB[1] = *reinterpret_cast<const bf16x8*>(qr + 32 + quad * 8);

    f32x4 o[4];
    #pragma unroll
    for (int dt = 0; dt < 4; ++dt)
        #pragma unroll
        for (int r = 0; r < 4; ++r) o[dt][r] = 0.0f;
    float lpart = 0.0f;

    auto stage = [&](int buf, int kt) {
        const int k0 = kt * 64;
        #pragma unroll
        for (int i = 0; i < 2; ++i) {
            int c = w * 2 + i;
            gl2lds16(Kb  + (size_t)(k0 + c * 8 + srow) * DKV + kvh * HD + soct, &Ks[buf][c * 512]);
            gl2lds16(VtG + (size_t)(kvh * HD + c * 8 + srow) * 2048 + k0 + soct, &Vt[buf][c * 512]);
        }
    };

    stage(0, 0);
    stage(1, 1);
    int cur = 0;
    for (int kt = 0; kt <= qt; ++kt) {
        if (kt < qt) asm volatile("s_waitcnt vmcnt(4)" ::: "memory");
        else         asm volatile("s_waitcnt vmcnt(0)" ::: "memory");
        __builtin_amdgcn_s_barrier();
        asm volatile("" ::: "memory");
        if (kt + 2 <= qt) {
            int tgt = (cur == 0) ? 2 : cur - 1;
            stage(tgt, kt + 2);
        }
        const u16* ksb = Ks[cur];
        const u16* vtb = Vt[cur];

        f32x4 s[4];
        #pragma unroll
        for (int kt4 = 0; kt4 < 4; ++kt4)
            #pragma unroll
            for (int r = 0; r < 4; ++r) s[kt4][r] = 0.0f;
        __builtin_amdgcn_s_setprio(1);
        #pragma unroll
        for (int ks = 0; ks < 2; ++ks) {
            const int kk0 = ks * 32 + quad * 8;
            #pragma unroll
            for (int kt4 = 0; kt4 < 4; ++kt4) {
                bf16x8 ka = *reinterpret_cast<const bf16x8*>(&ksb[lds_off(kt4 * 16 + l15, kk0)]);
                s[kt4] = __builtin_amdgcn_mfma_f32_16x16x32_bf16(ka, qB[ks], s[kt4], 0, 0, 0);
            }
        }
        __builtin_amdgcn_s_setprio(0);

        if (kt == qt) {
            const int qi = w * 16 + l15;
            #pragma unroll
            for (int kt4 = 0; kt4 < 4; ++kt4)
                #pragma unroll
                for (int r = 0; r < 4; ++r)
                    if ((kt4 * 16 + quad * 4 + r) > qi) s[kt4][r] = -1e30f;
        }

        u32 pb[4][2];
        #pragma unroll
        for (int kt4 = 0; kt4 < 4; ++kt4) {
            float p[4];
            #pragma unroll
            for (int r = 0; r < 4; ++r) {
                p[r] = exp2f(s[kt4][r] - 24.0f);
                lpart += p[r];
            }
            pb[kt4][0] = __builtin_amdgcn_perm(fbits(p[1]), fbits(p[0]), 0x07060302u);
            pb[kt4][1] = __builtin_amdgcn_perm(fbits(p[3]), fbits(p[2]), 0x07060302u);
        }

        __builtin_amdgcn_s_setprio(1);
        #pragma unroll
        for (int pair = 0; pair < 2; ++pair) {
            union { bf16x8 v; u32 u[4]; } pu;
            pu.u[0] = pb[pair * 2][0];     pu.u[1] = pb[pair * 2][1];
            pu.u[2] = pb[pair * 2 + 1][0]; pu.u[3] = pb[pair * 2 + 1][1];
            const int kk0 = (quad * 2 + pair) * 8;
            #pragma unroll
            for (int dt = 0; dt < 4; ++dt) {
                bf16x8 va = *reinterpret_cast<const bf16x8*>(&vtb[lds_off(dt * 16 + l15, kk0)]);
                o[dt] = __builtin_amdgcn_mfma_f32_16x16x32_bf16(va, pu.v, o[dt], 0, 0, 0);
            }
        }
        __builtin_amdgcn_s_setprio(0);

        cur = (cur == 2) ? 0 : cur + 1;
    }

    lpart += __shfl_xor(lpart, 16);
    lpart += __shfl_xor(lpart, 32);
    float inv = 1.0f / lpart;

    #pragma unroll
    for (int dt = 0; dt < 4; ++dt) {
        ushort4 ov;
        ov.x = f2b(o[dt][0] * inv);
        ov.y = f2b(o[dt][1] * inv);
        ov.z = f2b(o[dt][2] * inv);
        ov.w = f2b(o[dt][3] * inv);
        *reinterpret_cast<ushort4*>(attnb + (size_t)qrow * DQ + h * HD + dt * 16 + quad * 4) = ov;
    }
}

// ---------------------------------------------------------------------------
extern "C" void kernel_launch(void* const* d_in, const int* in_sizes, int n_in,
                              void* d_out, int out_size, void* d_ws, size_t ws_size,
                              hipStream_t stream) {
    const float* x    = (const float*)d_in[0];
    const float* cosb = (const float*)d_in[1];
    const float* sinb = (const float*)d_in[2];
    const float* wq   = (const float*)d_in[3];
    const float* wk   = (const float*)d_in[4];
    const float* wv   = (const float*)d_in[5];
    const float* wo   = (const float*)d_in[6];
    const float* qnw  = (const float*)d_in[7];
    const float* knw  = (const float*)d_in[8];
    float* out = (float*)d_out;

    char* ws = (char*)d_ws;
    const size_t MB = 1024 * 1024;
    u16* xb    = (u16*)(ws + 0);          // 8 MB
    u16* wqkvT = (u16*)(ws + 8  * MB);    // 12 MB: [wq^T; wk^T; wv^T] [3072][2048]
    u16* woT   = (u16*)(ws + 20 * MB);    // 8 MB
    u16* Qb    = (u16*)(ws + 28 * MB);    // 8 MB
    u16* Kb    = (u16*)(ws + 36 * MB);    // 2 MB
    u16* VtG   = (u16*)(ws + 38 * MB);    // 2 MB  [512][2048] col-interleaved
    u16* attnb = (u16*)(ws + 40 * MB);    // 8 MB
    u16* Pq    = (u16*)(ws + 48 * MB);    // 2 x 12 MB bf16 QKV partials (48-72.2)
    u16* Po    = (u16*)(ws + 48 * MB);    // 2 x 8 MB bf16 out partials -- ALIASES
                                          // Pq, which is dead after qkv_reduce
                                          // (gemm_outk runs after attn_fused).
                                          // peak ws use ~73 MB.

    // 1) prep: cast x + weight transposes
    prep<<<14336, 256, 0, stream>>>(x, wq, wk, wv, wo, xb, wqkvT, woT);

    // 2a) QKV projection, split-K=2, bf16 partials: 768 blocks = 3/CU
    gemm_splitk<<<dim3(3072 / 128, SEQLEN / 128, 2), 256, 0, stream>>>(
        xb, wqkvT, Pq);

    // 2b) reduce + fused RMSNorm/RoPE/V-interleave epilogue
    qkv_reduce<<<dim3(SEQLEN / 64, 48), 256, 0, stream>>>(
        Pq, Qb, Kb, VtG, cosb, sinb, qnw, knw);

    // 3) GQA causal flash attention v6 (+setprio)
    attn_fused<<<1024, 256, 0, stream>>>(Qb, Kb, VtG, attnb);

    // 4a) output projection, split-K=2, bf16 partials: 1024 blocks = 4/CU
    gemm_outk<<<dim3(DIN / 128, SEQLEN / 64, 2), 256, 0, stream>>>(
        attnb, woT, Po);

    // 4b) out = P0 + P1 (fp32)
    out_reduce<<<2048, 256, 0, stream>>>(Po, out);
}